// Round 1
// 381.154 us; speedup vs baseline: 1.0069x; 1.0069x over previous
//
#include <hip/hip_runtime.h>
#include <hip/hip_bf16.h>
#include <stdint.h>

typedef __attribute__((ext_vector_type(8))) short short8;
typedef __attribute__((ext_vector_type(4))) short short4v;
typedef __attribute__((ext_vector_type(4))) float f32x4;

#define HEADS 16
#define HDIM  128
#define BB    2
#define TT    2048
#define DMODEL 2048
#define INNER 2048
#define E3    6144
#define NTOK  (BB*TT)

__device__ inline void store1(__hip_bfloat16* p, float v) { *p = __float2bfloat16(v); }
__device__ inline void store1(float* p, float v)          { *p = v; }

__device__ inline short bfbits(float v) {
  __hip_bfloat16 h = __float2bfloat16(v);
  return *(short*)&h;
}

// async global->LDS, 16 B per lane. LDS dest is wave-uniform base + lane*16.
__device__ inline void gl_lds16(const __hip_bfloat16* g, __hip_bfloat16* l) {
  __builtin_amdgcn_global_load_lds(
      (const __attribute__((address_space(1))) void*)g,
      (__attribute__((address_space(3))) void*)l, 16, 0, 0);
}

__device__ inline void cvt8(const float* in, __hip_bfloat16* out, int i) {
  float4 a = *(const float4*)(in + i);
  float4 b = *(const float4*)(in + i + 4);
  short8 r;
  r[0]=bfbits(a.x); r[1]=bfbits(a.y); r[2]=bfbits(a.z); r[3]=bfbits(a.w);
  r[4]=bfbits(b.x); r[5]=bfbits(b.y); r[6]=bfbits(b.z); r[7]=bfbits(b.w);
  *(short8*)(out + i) = r;
}

// ---------------------------------------------------------------------------
// prep: cvt x->bf16 (4096 blocks), cvt Wqkv->bf16 (6144 blocks),
//       fill rope table cos/sin (512 blocks). One launch.
// ---------------------------------------------------------------------------
#define NBX   (NTOK*DMODEL/2048)    // 4096
#define NBW   (E3*DMODEL/2048)      // 6144
#define NBT   (TT*64/256)           // 512
__global__ __launch_bounds__(256)
void prep(const float* __restrict__ x, const float* __restrict__ Wqkv,
          __hip_bfloat16* __restrict__ xb, __hip_bfloat16* __restrict__ Wqkvb,
          float2* __restrict__ tab)
{
  const int tid = threadIdx.x;
  int blk = blockIdx.x;
  if (blk < NBX) {
    cvt8(x, xb, (blk*256 + tid)*8);
  } else if (blk < NBX + NBW) {
    cvt8(Wqkv, Wqkvb, ((blk-NBX)*256 + tid)*8);
  } else {
    int idx = (blk - NBX - NBW)*256 + tid;   // 0..131071
    int t  = idx >> 6;
    int d2 = idx & 63;
    float inv = powf(10000.f, -(float)d2 * (1.f/64.f));
    float ang = (float)t * inv;
    tab[idx] = make_float2(cosf(ang), sinf(ang));
  }
}

// ---------------------------------------------------------------------------
// fp32 -> bf16 pack, 8 elems/thread (for Wproj, after gemm_qkv frees its slot)
// ---------------------------------------------------------------------------
__global__ __launch_bounds__(256)
void cvt_bf16(const float* __restrict__ in, __hip_bfloat16* __restrict__ out, int n)
{
  int i = (blockIdx.x * 256 + threadIdx.x) * 8;
  if (i >= n) return;
  cvt8(in, out, i);
}

// ---------------------------------------------------------------------------
// m97-style GEMM (output projection): C[M][N] = sum_k A[m][k]*B[n][k].
// ---------------------------------------------------------------------------
template<typename TC>
__global__ __launch_bounds__(256, 2)
void gemm_lds(const __hip_bfloat16* __restrict__ A,
              const __hip_bfloat16* __restrict__ B,
              TC* __restrict__ C,
              int M, int N, int K)
{
  __shared__ __hip_bfloat16 sA[128*32];
  __shared__ __hip_bfloat16 sB[128*32];
  const int tid  = threadIdx.x;
  const int lane = tid & 63;
  const int wv   = tid >> 6;
  const int lm   = lane & 15;
  const int quad = lane >> 4;
  const int wm   = (wv >> 1) * 64;
  const int wn   = (wv & 1) * 64;
  const int bm   = blockIdx.y * 128;
  const int bn   = blockIdx.x * 128;

  f32x4 acc[4][4];
  #pragma unroll
  for (int i=0;i<4;i++)
    #pragma unroll
    for (int j=0;j<4;j++) acc[i][j] = (f32x4){0.f,0.f,0.f,0.f};

  const int srow = wv*32 + (lane >> 2);
  const int scol = (lane & 3) * 8;
  const __hip_bfloat16* gA0 = A + (size_t)(bm + srow)*K + scol;
  const __hip_bfloat16* gA1 = gA0 + (size_t)16*K;
  const __hip_bfloat16* gB0 = B + (size_t)(bn + srow)*K + scol;
  const __hip_bfloat16* gB1 = gB0 + (size_t)16*K;
  __hip_bfloat16* lA0 = sA + wv*1024;
  __hip_bfloat16* lA1 = lA0 + 512;
  __hip_bfloat16* lB0 = sB + wv*1024;
  __hip_bfloat16* lB1 = lB0 + 512;

  for (int k0 = 0; k0 < K; k0 += 32) {
    __syncthreads();
    gl_lds16(gA0, lA0);
    gl_lds16(gA1, lA1);
    gl_lds16(gB0, lB0);
    gl_lds16(gB1, lB1);
    gA0 += 32; gA1 += 32; gB0 += 32; gB1 += 32;
    __syncthreads();
    short8 af[4], bf[4];
    #pragma unroll
    for (int t=0;t<4;t++)
      af[t] = *(const short8*)(sA + (wm + t*16 + lm)*32 + quad*8);
    #pragma unroll
    for (int t=0;t<4;t++)
      bf[t] = *(const short8*)(sB + (wn + t*16 + lm)*32 + quad*8);
    #pragma unroll
    for (int i=0;i<4;i++)
      #pragma unroll
      for (int j=0;j<4;j++)
        acc[i][j] = __builtin_amdgcn_mfma_f32_16x16x32_bf16(af[i], bf[j], acc[i][j], 0,0,0);
  }

  const int row0 = bm + wm + quad*4;
  const int col0 = bn + wn + lm;
  #pragma unroll
  for (int i=0;i<4;i++)
    #pragma unroll
    for (int j=0;j<4;j++)
      #pragma unroll
      for (int r=0;r<4;r++)
        store1(C + (size_t)(row0 + i*16 + r)*N + col0 + j*16, acc[i][j][r]);
}

// ---------------------------------------------------------------------------
// QKV GEMM, 256x256 tile, 8-wave, BK=64, 8-phase schedule (T2+T3+T4+T5):
//  - LDS 128 KiB: 2 bufs x (A half0, A half1, B half0, B half1) x 16 KiB
//  - k-chunk XOR swizzle (kc ^= row&7), inverse applied on global source so
//    global_load_lds stays linear-dest (rule: both-sides-or-neither)
//  - counted s_waitcnt vmcnt(4) once per K-tile; never drains in main loop
//  - B-staging rows bit-permuted for Q/K so each wave owns both RoPE halves:
//    acc[i][j] pairs with acc[i][j+2] -> RoPE fully in-register, no sT.
// ---------------------------------------------------------------------------
__global__ __launch_bounds__(512, 2)
void gemm_qkv2(const __hip_bfloat16* __restrict__ A,
               const __hip_bfloat16* __restrict__ B,
               const float2* __restrict__ tab,
               __hip_bfloat16* __restrict__ Qh,
               __hip_bfloat16* __restrict__ Kh,
               __hip_bfloat16* __restrict__ Vt)
{
  __shared__ __align__(128) __hip_bfloat16 smem[65536];   // 128 KiB
  const int tid  = threadIdx.x;
  const int lane = tid & 63;
  const int w    = tid >> 6;        // wave 0..7
  const int lm   = lane & 15;
  const int quad = lane >> 4;
  const int wm   = w >> 2;          // 0..1  (M half)
  const int wn   = w & 3;           // 0..3  (N quarter)

  // XCD-aware bijective swizzle: 384 blocks, 8 XCDs, 48 contiguous tiles/XCD.
  const int flat  = blockIdx.x;
  const int wgid  = (flat & 7) * 48 + (flat >> 3);
  const int tileN = wgid >> 4;      // 0..23  (B-panel reuse within XCD)
  const int tileM = wgid & 15;      // 0..15
  const int bm    = tileM << 8;
  const int bn    = tileN << 8;
  const int type  = bn >> 11;       // 0=Q 1=K 2=V

  // ---- staging source descriptors (per thread, 2 chunks of 16 B each) ----
  const int r0 = tid >> 3;                  // row within 64-row chunk group
  const int kc = (tid & 7) ^ (r0 & 7);      // inverse-swizzled k-chunk
  size_t gA[2][2], gB[2][2];
  #pragma unroll
  for (int h = 0; h < 2; ++h)
    #pragma unroll
    for (int j = 0; j < 2; ++j) {
      gA[h][j] = ((size_t)(bm + h*128 + j*64 + r0) << 11) + kc*8;
      int prow;
      if (type < 2)   // RoPE-pair permutation (bijective bit shuffle)
        prow = h*128 + j*32 + ((r0 >> 5) << 6) + (((r0 >> 4) & 1) << 4) + (r0 & 15);
      else            // identity for V
        prow = h*128 + j*64 + r0;
      gB[h][j] = ((size_t)(bn + prow) << 11) + kc*8;
    }
  const int ldsW = w * 512;         // wave-uniform lane-group base (elements)

#define STAGE_A(h, ktt, bb_) do { \
    __hip_bfloat16* _l = smem + (bb_)*32768 + (h)*8192 + ldsW; \
    gl_lds16(A + gA[h][0] + (size_t)(ktt)*64, _l); \
    gl_lds16(A + gA[h][1] + (size_t)(ktt)*64, _l + 4096); \
  } while (0)
#define STAGE_B(h, ktt, bb_) do { \
    __hip_bfloat16* _l = smem + (bb_)*32768 + 16384 + (h)*8192 + ldsW; \
    gl_lds16(B + gB[h][0] + (size_t)(ktt)*64, _l); \
    gl_lds16(B + gB[h][1] + (size_t)(ktt)*64, _l + 4096); \
  } while (0)

  // ---- fragment-read LDS offsets (elements); row&7 == lm&7 for all frags ----
  const int xk0 = ((quad      ^ (lm & 7)) << 3);   // k_sub 0
  const int xk1 = (((quad|4)  ^ (lm & 7)) << 3);   // k_sub 1
  const int aRow = wm*8192 + lm*64;                           // + f*1024
  const int bRow = 16384 + (wn>>1)*8192 + (wn&1)*4096 + lm*64; // + f*1024

  f32x4 acc[8][4];
  #pragma unroll
  for (int i=0;i<8;i++)
    #pragma unroll
    for (int j=0;j<4;j++) acc[i][j] = (f32x4){0.f,0.f,0.f,0.f};

  // ---- prologue: tile0 fully + B(1); leave B(1) (4 loads) in flight ----
  STAGE_A(0, 0, 0); STAGE_A(1, 0, 0);
  STAGE_B(0, 0, 0); STAGE_B(1, 0, 0);
  STAGE_B(0, 1, 1); STAGE_B(1, 1, 1);
  asm volatile("s_waitcnt vmcnt(4)" ::: "memory");
  __builtin_amdgcn_s_barrier();

  #pragma unroll 2
  for (int kt = 0; kt < 32; ++kt) {
    const int cb   = kt & 1;
    const int nb   = cb ^ 1;
    const int cOff = cb * 32768;
    short8 bfrag[4][2];
    #pragma unroll
    for (int q = 0; q < 4; ++q) {
      // ---- ds reads for this phase ----
      if (q == 0) {
        #pragma unroll
        for (int f = 0; f < 4; ++f) {
          bfrag[f][0] = *(const short8*)(smem + cOff + bRow + f*1024 + xk0);
          bfrag[f][1] = *(const short8*)(smem + cOff + bRow + f*1024 + xk1);
        }
      }
      short8 a0s0 = *(const short8*)(smem + cOff + aRow + (q*2+0)*1024 + xk0);
      short8 a0s1 = *(const short8*)(smem + cOff + aRow + (q*2+0)*1024 + xk1);
      short8 a1s0 = *(const short8*)(smem + cOff + aRow + (q*2+1)*1024 + xk0);
      short8 a1s1 = *(const short8*)(smem + cOff + aRow + (q*2+1)*1024 + xk1);
      // ---- stage issues (schedule: A(t+1)@q0 -> other buf; B(t+2)@q1,q2 ----
      // into CURRENT buf, safe: all B-frags register-resident after q0) ----
      if (q == 0)      { if (kt + 1 < 32) { STAGE_A(0, kt+1, nb); STAGE_A(1, kt+1, nb); } }
      else if (q == 1) { if (kt + 2 < 32) STAGE_B(0, kt+2, cb); }
      else if (q == 2) { if (kt + 2 < 32) STAGE_B(1, kt+2, cb); }
      __builtin_amdgcn_s_barrier();
      __builtin_amdgcn_s_setprio(1);
      #pragma unroll
      for (int nf = 0; nf < 4; ++nf) {
        acc[q*2+0][nf] = __builtin_amdgcn_mfma_f32_16x16x32_bf16(a0s0, bfrag[nf][0], acc[q*2+0][nf], 0,0,0);
        acc[q*2+0][nf] = __builtin_amdgcn_mfma_f32_16x16x32_bf16(a0s1, bfrag[nf][1], acc[q*2+0][nf], 0,0,0);
        acc[q*2+1][nf] = __builtin_amdgcn_mfma_f32_16x16x32_bf16(a1s0, bfrag[nf][0], acc[q*2+1][nf], 0,0,0);
        acc[q*2+1][nf] = __builtin_amdgcn_mfma_f32_16x16x32_bf16(a1s1, bfrag[nf][1], acc[q*2+1][nf], 0,0,0);
      }
      __builtin_amdgcn_s_setprio(0);
      if (q < 3) {
        __builtin_amdgcn_s_barrier();
      } else {
        // K-tile boundary: wait for tile kt+1 (A issued @q0, B two tiles ago),
        // leave B(kt+2) (4 loads) in flight. Epilogue drains to 0.
        if (kt < 30) asm volatile("s_waitcnt vmcnt(4)" ::: "memory");
        else         asm volatile("s_waitcnt vmcnt(0)" ::: "memory");
        __builtin_amdgcn_s_barrier();
      }
    }
  }
#undef STAGE_A
#undef STAGE_B

  // ================= epilogue (all in registers, no LDS) =================
  const float SCQ = 0.08838834764831845f * 1.4426950408889634f;  // scale*log2(e)
  const int tok0 = bm + wm*128;
  if (type < 2) {
    __hip_bfloat16* const dst = (type == 0) ? Qh : Kh;
    const float mul = (type == 0) ? SCQ : 1.0f;
    const int head = ((bn & 2047) >> 7) + (wn >> 1);
    const int d2b  = (wn & 1)*32 + lm;
    #pragma unroll
    for (int i = 0; i < 8; ++i) {
      #pragma unroll
      for (int r = 0; r < 4; ++r) {
        const int t  = tok0 + i*16 + quad*4 + r;
        const int b  = t >> 11;
        const int tl = t & (TT-1);
        const float2* tp = tab + (size_t)tl*64;
        __hip_bfloat16* const o = dst + ((size_t)(b*HEADS + head)*TT + tl)*HDIM;
        #pragma unroll
        for (int j = 0; j < 2; ++j) {
          const int d2 = d2b + j*16;
          const float2 cs = tp[d2];
          const float v1 = acc[i][j  ][r];
          const float v2 = acc[i][j+2][r];
          o[d2]      = __float2bfloat16((v1*cs.x - v2*cs.y) * mul);
          o[d2 + 64] = __float2bfloat16((v2*cs.x + v1*cs.y) * mul);
        }
      }
    }
  } else {
    const int fcb = (bn & 2047) + wn*64 + lm;
    #pragma unroll
    for (int i = 0; i < 8; ++i) {
      const int t0 = tok0 + i*16 + quad*4;
      const int b  = t0 >> 11;
      const int tl = t0 & (TT-1);
      #pragma unroll
      for (int j = 0; j < 4; ++j) {
        const int c    = fcb + j*16;
        const int head = c >> 7;
        const int d    = c & 127;
        short4v o;
        #pragma unroll
        for (int r = 0; r < 4; ++r) o[r] = bfbits(acc[i][j][r]);
        *(short4v*)(Vt + ((size_t)(b*HEADS + head)*HDIM + d)*TT + tl) = o;
      }
    }
  }
}

// ---------------------------------------------------------------------------
// Causal flash attention, paired q-tiles processed sequentially (uniform work,
// no spill). Fixed-max softmax p = 2^(s' - FML2), Q pre-scaled by scale*log2e.
// ---------------------------------------------------------------------------
__global__ __launch_bounds__(256, 3)
void flash_attn(const __hip_bfloat16* __restrict__ Qh,
                const __hip_bfloat16* __restrict__ Kh,
                const __hip_bfloat16* __restrict__ Vt,
                __hip_bfloat16* __restrict__ Out)
{
  const int tid  = threadIdx.x;
  const int lane = tid & 63;
  const int wv   = tid >> 6;
  const int lm   = lane & 15;
  const int quad = lane >> 4;
  const int jA   = blockIdx.x;            // 0..15
  const int bh   = blockIdx.y;
  const int b    = bh >> 4;
  const int h    = bh & 15;

  __shared__ __hip_bfloat16 sK[64*136];
  __shared__ __hip_bfloat16 sV[128*72];
  __shared__ __hip_bfloat16 sP[4][16*72];

  const float FML2 = 8.0f * 1.4426950408889634f;

  const int rk0 = tid >> 4;
  const int ck  = (tid & 15) * 8;
  const int dv0 = tid >> 3;
  const int cv  = (tid & 7) * 8;
  const __hip_bfloat16* KpBase = Kh + (size_t)bh*TT*HDIM + (size_t)rk0*HDIM + ck;
  const __hip_bfloat16* VpBase = Vt + (size_t)bh*HDIM*TT + (size_t)dv0*TT + cv;

  #pragma unroll
  for (int pass = 0; pass < 2; ++pass) {
    const int q0 = (pass == 0 ? jA : 31 - jA) * 64;

    short8 aq[4];
    {
      const __hip_bfloat16* qp = Qh + ((size_t)bh*TT + q0 + wv*16 + lm)*HDIM + quad*8;
      #pragma unroll
      for (int kd=0;kd<4;kd++) aq[kd] = *(const short8*)(qp + kd*32);
    }

    float l_p[4] = {0,0,0,0};
    f32x4 acc_o[8];
    #pragma unroll
    for (int i=0;i<8;i++) acc_o[i] = (f32x4){0.f,0.f,0.f,0.f};

    const __hip_bfloat16* Kp = KpBase;
    const __hip_bfloat16* Vp = VpBase;
    short8 pk[4], pv[4];
    #pragma unroll
    for (int it=0;it<4;++it) {
      pk[it] = *(const short8*)(Kp + (size_t)it*16*HDIM);
      pv[it] = *(const short8*)(Vp + (size_t)it*32*TT);
    }
    Kp += (size_t)64*HDIM; Vp += 64;

    for (int kv0 = 0; kv0 <= q0; kv0 += 64) {
      __syncthreads();
      #pragma unroll
      for (int it=0;it<4;++it) {
        *(short8*)(&sK[(it*16 + rk0)*136 + ck]) = pk[it];
        *(short8*)(&sV[(it*32 + dv0)*72 + cv])  = pv[it];
      }
      if (kv0 + 64 <= q0) {
        #pragma unroll
        for (int it=0;it<4;++it) {
          pk[it] = *(const short8*)(Kp + (size_t)it*16*HDIM);
          pv[it] = *(const short8*)(Vp + (size_t)it*32*TT);
        }
        Kp += (size_t)64*HDIM; Vp += 64;
      }
      __syncthreads();

      f32x4 accs[4];
      #pragma unroll
      for (int nt=0;nt<4;nt++) accs[nt] = (f32x4){0.f,0.f,0.f,0.f};
      #pragma unroll
      for (int kd=0;kd<4;kd++)
        #pragma unroll
        for (int nt=0;nt<4;nt++) {
          short8 bk = *(const short8*)(&sK[(nt*16 + lm)*136 + kd*32 + quad*8]);
          accs[nt] = __builtin_amdgcn_mfma_f32_16x16x32_bf16(aq[kd], bk, accs[nt], 0,0,0);
        }

      const int rowb = q0 + wv*16 + quad*4;
      const bool diag = (kv0 == q0);
      #pragma unroll
      for (int nt=0;nt<4;nt++)
        #pragma unroll
        for (int r=0;r<4;r++) {
          float p = exp2f(accs[nt][r] - FML2);
          if (diag && (kv0 + nt*16 + lm > rowb + r)) p = 0.f;
          l_p[r] += p;
          sP[wv][(quad*4 + r)*72 + nt*16 + lm] = __float2bfloat16(p);
        }

      #pragma unroll
      for (int kd2=0;kd2<2;kd2++) {
        short8 ap = *(const short8*)(&sP[wv][lm*72 + kd2*32 + quad*8]);
        #pragma unroll
        for (int nt2=0;nt2<8;nt2++) {
          short8 bvv = *(const short8*)(&sV[(nt2*16 + lm)*72 + kd2*32 + quad*8]);
          acc_o[nt2] = __builtin_amdgcn_mfma_f32_16x16x32_bf16(ap, bvv, acc_o[nt2], 0,0,0);
        }
      }
    }

    #pragma unroll
    for (int off=1; off<16; off<<=1)
      #pragma unroll
      for (int r=0;r<4;r++) l_p[r] += __shfl_xor(l_p[r], off);
    #pragma unroll
    for (int r=0;r<4;r++) l_p[r] = 1.f / l_p[r];

    #pragma unroll
    for (int nt2=0;nt2<8;nt2++)
      #pragma unroll
      for (int r=0;r<4;r++) {
        int t = q0 + wv*16 + quad*4 + r;
        Out[((size_t)b*TT + t)*INNER + (size_t)h*HDIM + nt2*16 + lm] =
          __float2bfloat16(acc_o[nt2][r] * l_p[r]);
      }
  }
}

// ---------------------------------------------------------------------------
extern "C" void kernel_launch(void* const* d_in, const int* in_sizes, int n_in,
                              void* d_out, int out_size, void* d_ws, size_t ws_size,
                              hipStream_t stream)
{
  (void)in_sizes; (void)n_in; (void)out_size; (void)ws_size;
  const float* x     = (const float*)d_in[0];
  const float* Wqkv  = (const float*)d_in[1];
  const float* Wproj = (const float*)d_in[2];
  float* out = (float*)d_out;

  // Workspace (100.66 MB, R3-proven size):
  //  [0, 16.78): xb -> attn_out (xb dead after gemm_qkv)
  //  [16.78, 41.94): Wqkvb -> Wprojb overlay (Wqkvb dead after gemm_qkv)
  //  [41.94, 50.33): rope table (1 MB used; dead after gemm_qkv)
  //  [50.33, 67.11): Qh  [67.11, 83.89): Kh  [83.89, 100.66): Vt
  char* ws = (char*)d_ws;
  __hip_bfloat16* xb       = (__hip_bfloat16*)ws;
  __hip_bfloat16* attn_out = xb;
  char* p1 = ws + (size_t)NTOK*DMODEL*2;
  __hip_bfloat16* Wqkvb  = (__hip_bfloat16*)p1;
  __hip_bfloat16* Wprojb = (__hip_bfloat16*)p1;
  char* p2 = p1 + (size_t)E3*DMODEL*2;
  float2* ropeTab = (float2*)p2;
  char* p3 = p2 + (size_t)DMODEL*INNER*2;   // 8.39 MB slot (table uses 1 MB)
  const size_t hsz = (size_t)BB*HEADS*TT*HDIM*2;
  __hip_bfloat16* Qh = (__hip_bfloat16*)p3;
  __hip_bfloat16* Kh = (__hip_bfloat16*)(p3 + hsz);
  __hip_bfloat16* Vt = (__hip_bfloat16*)(p3 + 2*hsz);

  prep<<<dim3(NBX + NBW + NBT), dim3(256), 0, stream>>>(x, Wqkv, xb, Wqkvb, ropeTab);

  gemm_qkv2<<<dim3(384), dim3(512), 0, stream>>>(xb, Wqkvb, ropeTab, Qh, Kh, Vt);

  // Wqkvb + table dead; overlay Wprojb.
  cvt_bf16<<<dim3(DMODEL*INNER/2048), dim3(256), 0, stream>>>(Wproj, Wprojb, DMODEL*INNER);

  flash_attn<<<dim3(TT/128, BB*HEADS), dim3(256), 0, stream>>>(Qh, Kh, Vt, attn_out);

  gemm_lds<float>
    <<<dim3(INNER/128, NTOK/128), dim3(256), 0, stream>>>(attn_out, Wprojb, out, NTOK, INNER, DMODEL);
}

// Round 2
// 378.391 us; speedup vs baseline: 1.0143x; 1.0073x over previous
//
#include <hip/hip_runtime.h>
#include <hip/hip_bf16.h>
#include <stdint.h>

typedef __attribute__((ext_vector_type(8))) short short8;
typedef __attribute__((ext_vector_type(4))) short short4v;
typedef __attribute__((ext_vector_type(4))) float f32x4;

#define HEADS 16
#define HDIM  128
#define BB    2
#define TT    2048
#define DMODEL 2048
#define INNER 2048
#define E3    6144
#define NTOK  (BB*TT)

__device__ inline void store1(__hip_bfloat16* p, float v) { *p = __float2bfloat16(v); }
__device__ inline void store1(float* p, float v)          { *p = v; }

__device__ inline short bfbits(float v) {
  __hip_bfloat16 h = __float2bfloat16(v);
  return *(short*)&h;
}

// async global->LDS, 16 B per lane. LDS dest is wave-uniform base + lane*16.
__device__ inline void gl_lds16(const __hip_bfloat16* g, __hip_bfloat16* l) {
  __builtin_amdgcn_global_load_lds(
      (const __attribute__((address_space(1))) void*)g,
      (__attribute__((address_space(3))) void*)l, 16, 0, 0);
}

__device__ inline void cvt8(const float* in, __hip_bfloat16* out, int i) {
  float4 a = *(const float4*)(in + i);
  float4 b = *(const float4*)(in + i + 4);
  short8 r;
  r[0]=bfbits(a.x); r[1]=bfbits(a.y); r[2]=bfbits(a.z); r[3]=bfbits(a.w);
  r[4]=bfbits(b.x); r[5]=bfbits(b.y); r[6]=bfbits(b.z); r[7]=bfbits(b.w);
  *(short8*)(out + i) = r;
}

// ---------------------------------------------------------------------------
// prep: cvt x->bf16 (4096 blocks), cvt Wqkv->bf16 (6144 blocks),
//       fill rope table cos/sin (512 blocks). One launch.
// ---------------------------------------------------------------------------
#define NBX   (NTOK*DMODEL/2048)    // 4096
#define NBW   (E3*DMODEL/2048)      // 6144
#define NBT   (TT*64/256)           // 512
__global__ __launch_bounds__(256)
void prep(const float* __restrict__ x, const float* __restrict__ Wqkv,
          __hip_bfloat16* __restrict__ xb, __hip_bfloat16* __restrict__ Wqkvb,
          float2* __restrict__ tab)
{
  const int tid = threadIdx.x;
  int blk = blockIdx.x;
  if (blk < NBX) {
    cvt8(x, xb, (blk*256 + tid)*8);
  } else if (blk < NBX + NBW) {
    cvt8(Wqkv, Wqkvb, ((blk-NBX)*256 + tid)*8);
  } else {
    int idx = (blk - NBX - NBW)*256 + tid;   // 0..131071
    int t  = idx >> 6;
    int d2 = idx & 63;
    float inv = powf(10000.f, -(float)d2 * (1.f/64.f));
    float ang = (float)t * inv;
    tab[idx] = make_float2(cosf(ang), sinf(ang));
  }
}

// ---------------------------------------------------------------------------
// fp32 -> bf16 pack, 8 elems/thread (for Wproj, after gemm_qkv frees its slot)
// ---------------------------------------------------------------------------
__global__ __launch_bounds__(256)
void cvt_bf16(const float* __restrict__ in, __hip_bfloat16* __restrict__ out, int n)
{
  int i = (blockIdx.x * 256 + threadIdx.x) * 8;
  if (i >= n) return;
  cvt8(in, out, i);
}

// ---------------------------------------------------------------------------
// m97-style GEMM (output projection): C[M][N] = sum_k A[m][k]*B[n][k].
// ---------------------------------------------------------------------------
template<typename TC>
__global__ __launch_bounds__(256, 2)
void gemm_lds(const __hip_bfloat16* __restrict__ A,
              const __hip_bfloat16* __restrict__ B,
              TC* __restrict__ C,
              int M, int N, int K)
{
  __shared__ __hip_bfloat16 sA[128*32];
  __shared__ __hip_bfloat16 sB[128*32];
  const int tid  = threadIdx.x;
  const int lane = tid & 63;
  const int wv   = tid >> 6;
  const int lm   = lane & 15;
  const int quad = lane >> 4;
  const int wm   = (wv >> 1) * 64;
  const int wn   = (wv & 1) * 64;
  const int bm   = blockIdx.y * 128;
  const int bn   = blockIdx.x * 128;

  f32x4 acc[4][4];
  #pragma unroll
  for (int i=0;i<4;i++)
    #pragma unroll
    for (int j=0;j<4;j++) acc[i][j] = (f32x4){0.f,0.f,0.f,0.f};

  const int srow = wv*32 + (lane >> 2);
  const int scol = (lane & 3) * 8;
  const __hip_bfloat16* gA0 = A + (size_t)(bm + srow)*K + scol;
  const __hip_bfloat16* gA1 = gA0 + (size_t)16*K;
  const __hip_bfloat16* gB0 = B + (size_t)(bn + srow)*K + scol;
  const __hip_bfloat16* gB1 = gB0 + (size_t)16*K;
  __hip_bfloat16* lA0 = sA + wv*1024;
  __hip_bfloat16* lA1 = lA0 + 512;
  __hip_bfloat16* lB0 = sB + wv*1024;
  __hip_bfloat16* lB1 = lB0 + 512;

  for (int k0 = 0; k0 < K; k0 += 32) {
    __syncthreads();
    gl_lds16(gA0, lA0);
    gl_lds16(gA1, lA1);
    gl_lds16(gB0, lB0);
    gl_lds16(gB1, lB1);
    gA0 += 32; gA1 += 32; gB0 += 32; gB1 += 32;
    __syncthreads();
    short8 af[4], bf[4];
    #pragma unroll
    for (int t=0;t<4;t++)
      af[t] = *(const short8*)(sA + (wm + t*16 + lm)*32 + quad*8);
    #pragma unroll
    for (int t=0;t<4;t++)
      bf[t] = *(const short8*)(sB + (wn + t*16 + lm)*32 + quad*8);
    #pragma unroll
    for (int i=0;i<4;i++)
      #pragma unroll
      for (int j=0;j<4;j++)
        acc[i][j] = __builtin_amdgcn_mfma_f32_16x16x32_bf16(af[i], bf[j], acc[i][j], 0,0,0);
  }

  const int row0 = bm + wm + quad*4;
  const int col0 = bn + wn + lm;
  #pragma unroll
  for (int i=0;i<4;i++)
    #pragma unroll
    for (int j=0;j<4;j++)
      #pragma unroll
      for (int r=0;r<4;r++)
        store1(C + (size_t)(row0 + i*16 + r)*N + col0 + j*16, acc[i][j][r]);
}

// ---------------------------------------------------------------------------
// QKV GEMM, 128x256 tile, 8-wave, BK=64, 2-phase K-tile schedule.
//  - grid = 32 M-tiles x 24 N-tiles = 768 blocks = EXACTLY 3 rounds of 256 CUs
//    (the 256x256 version's 384 blocks = 1.5 rounds wasted 25% of the chip).
//  - LDS 96 KiB: 2 bufs x (A 16 KiB + B 32 KiB); 1 block/CU.
//  - all 16 frag reads front-loaded at q0 (ksub0 first -> compiler's counted
//    lgkmcnt drains ksub1 reads under the first MFMA cluster).
//  - counted s_waitcnt vmcnt(2) at K-tile boundary (A of t+2 stays in flight).
//  - staging lifetime: every gl_lds targets a region whose last ds_read is
//    >=2 barriers earlier (B(t+1)->nb: read finished end of t-1;
//    A(t+2)->cb: read q0 of t, issued q1 of t).
//  - B-staging rows bit-permuted for Q/K so each wave owns both RoPE halves:
//    acc[i][j] pairs with acc[i][j+2] -> RoPE fully in-register.
// ---------------------------------------------------------------------------
__global__ __launch_bounds__(512, 2)
void gemm_qkv3(const __hip_bfloat16* __restrict__ A,
               const __hip_bfloat16* __restrict__ B,
               const float2* __restrict__ tab,
               __hip_bfloat16* __restrict__ Qh,
               __hip_bfloat16* __restrict__ Kh,
               __hip_bfloat16* __restrict__ Vt)
{
  __shared__ __align__(128) __hip_bfloat16 smem[49152];   // 96 KiB
  const int tid  = threadIdx.x;
  const int lane = tid & 63;
  const int w    = tid >> 6;        // wave 0..7
  const int lm   = lane & 15;
  const int quad = lane >> 4;
  const int wm   = w >> 2;          // 0..1  (M half: 64 rows)
  const int wn   = w & 3;           // 0..3  (N quarter: 64 cols)

  // XCD-aware bijective swizzle: 768 blocks, 8 XCDs, 96 contiguous tiles/XCD.
  // Within an XCD: 32 M-tiles share each of 3 N-panels (B-panel L2 reuse).
  const int flat  = blockIdx.x;
  const int wgid  = (flat & 7) * 96 + (flat >> 3);
  const int tileN = wgid >> 5;      // 0..23
  const int tileM = wgid & 31;      // 0..31
  const int bm    = tileM << 7;     // 128-row tiles
  const int bn    = tileN << 8;     // 256-col tiles
  const int type  = bn >> 11;       // 0=Q 1=K 2=V

  // ---- staging source descriptors ----
  const int r0 = tid >> 3;                  // row within 64-row chunk
  const int kc = (tid & 7) ^ (r0 & 7);      // inverse-swizzled k-chunk
  const size_t gA0 = ((size_t)(bm      + r0) << 11) + kc*8;
  const size_t gA1 = ((size_t)(bm + 64 + r0) << 11) + kc*8;
  size_t gB[2][2];
  #pragma unroll
  for (int h = 0; h < 2; ++h)
    #pragma unroll
    for (int j = 0; j < 2; ++j) {
      int prow;
      if (type < 2)   // RoPE-pair permutation (bijective bit shuffle)
        prow = h*128 + j*32 + ((r0 >> 5) << 6) + (((r0 >> 4) & 1) << 4) + (r0 & 15);
      else            // identity for V
        prow = h*128 + j*64 + r0;
      gB[h][j] = ((size_t)(bn + prow) << 11) + kc*8;
    }
  const int ldsW = w * 512;         // wave-uniform lane-group base (elements)

// buffer layout (elements): buf b at b*24576: A [0,8192) = 2 chunks of 4096;
//                                             B [8192,24576) = 4 chunks.
#define STAGE_A(ktt, bb_) do { \
    __hip_bfloat16* _l = smem + (bb_)*24576 + ldsW; \
    gl_lds16(A + gA0 + (size_t)(ktt)*64, _l); \
    gl_lds16(A + gA1 + (size_t)(ktt)*64, _l + 4096); \
  } while (0)
#define STAGE_B(h, ktt, bb_) do { \
    __hip_bfloat16* _l = smem + (bb_)*24576 + 8192 + (h)*8192 + ldsW; \
    gl_lds16(B + gB[h][0] + (size_t)(ktt)*64, _l); \
    gl_lds16(B + gB[h][1] + (size_t)(ktt)*64, _l + 4096); \
  } while (0)

  // ---- fragment-read LDS offsets (elements); chunk-row & 7 == lm & 7 ----
  const int xk0 = ((quad      ^ (lm & 7)) << 3);   // k_sub 0
  const int xk1 = (((quad|4)  ^ (lm & 7)) << 3);   // k_sub 1
  const int aRow = wm*4096 + lm*64;                            // + f*1024
  const int bRow = 8192 + (wn>>1)*8192 + (wn&1)*4096 + lm*64;  // + f*1024

  f32x4 acc[4][4];
  #pragma unroll
  for (int i=0;i<4;i++)
    #pragma unroll
    for (int j=0;j<4;j++) acc[i][j] = (f32x4){0.f,0.f,0.f,0.f};

  // ---- prologue: tile0 (6 loads) + A(1) (2 loads); leave A(1) in flight ----
  STAGE_A(0, 0);
  STAGE_B(0, 0, 0);
  STAGE_B(1, 0, 0);
  STAGE_A(1, 1);
  asm volatile("s_waitcnt vmcnt(2)" ::: "memory");
  __builtin_amdgcn_s_barrier();

  #pragma unroll 2
  for (int kt = 0; kt < 32; ++kt) {
    const int cb   = kt & 1;
    const int nb   = cb ^ 1;
    const int cOff = cb * 24576;

    // ---- q0: read ALL fragments (ksub0 first so MFMA0 can start early) ----
    short8 a0[4], b0[4], a1[4], b1[4];
    #pragma unroll
    for (int f = 0; f < 4; ++f) {
      a0[f] = *(const short8*)(smem + cOff + aRow + f*1024 + xk0);
      b0[f] = *(const short8*)(smem + cOff + bRow + f*1024 + xk0);
    }
    #pragma unroll
    for (int f = 0; f < 4; ++f) {
      a1[f] = *(const short8*)(smem + cOff + aRow + f*1024 + xk1);
      b1[f] = *(const short8*)(smem + cOff + bRow + f*1024 + xk1);
    }
    if (kt + 1 < 32) STAGE_B(0, kt+1, nb);
    __builtin_amdgcn_s_barrier();
    __builtin_amdgcn_s_setprio(1);
    #pragma unroll
    for (int i = 0; i < 4; ++i)
      #pragma unroll
      for (int j = 0; j < 4; ++j)
        acc[i][j] = __builtin_amdgcn_mfma_f32_16x16x32_bf16(a0[i], b0[j], acc[i][j], 0,0,0);
    __builtin_amdgcn_s_setprio(0);
    __builtin_amdgcn_s_barrier();

    // ---- q1 ----
    if (kt + 1 < 32) STAGE_B(1, kt+1, nb);
    if (kt + 2 < 32) STAGE_A(kt+2, cb);     // cb A-region fully read at q0
    __builtin_amdgcn_s_barrier();
    __builtin_amdgcn_s_setprio(1);
    #pragma unroll
    for (int i = 0; i < 4; ++i)
      #pragma unroll
      for (int j = 0; j < 4; ++j)
        acc[i][j] = __builtin_amdgcn_mfma_f32_16x16x32_bf16(a1[i], b1[j], acc[i][j], 0,0,0);
    __builtin_amdgcn_s_setprio(0);
    // K-tile boundary: drain A(kt+1)+B(kt+1) (6 oldest), keep A(kt+2) flying.
    if (kt < 30) asm volatile("s_waitcnt vmcnt(2)" ::: "memory");
    else         asm volatile("s_waitcnt vmcnt(0)" ::: "memory");
    __builtin_amdgcn_s_barrier();
  }
#undef STAGE_A
#undef STAGE_B

  // ================= epilogue (all in registers, no LDS) =================
  const float SCQ = 0.08838834764831845f * 1.4426950408889634f;  // scale*log2(e)
  const int tok0 = bm + wm*64;
  if (type < 2) {
    __hip_bfloat16* const dst = (type == 0) ? Qh : Kh;
    const float mul = (type == 0) ? SCQ : 1.0f;
    const int head = ((bn & 2047) >> 7) + (wn >> 1);
    const int d2b  = (wn & 1)*32 + lm;
    #pragma unroll
    for (int i = 0; i < 4; ++i) {
      #pragma unroll
      for (int r = 0; r < 4; ++r) {
        const int t  = tok0 + i*16 + quad*4 + r;
        const int b  = t >> 11;
        const int tl = t & (TT-1);
        const float2* tp = tab + (size_t)tl*64;
        __hip_bfloat16* const o = dst + ((size_t)(b*HEADS + head)*TT + tl)*HDIM;
        #pragma unroll
        for (int j = 0; j < 2; ++j) {
          const int d2 = d2b + j*16;
          const float2 cs = tp[d2];
          const float v1 = acc[i][j  ][r];
          const float v2 = acc[i][j+2][r];
          o[d2]      = __float2bfloat16((v1*cs.x - v2*cs.y) * mul);
          o[d2 + 64] = __float2bfloat16((v2*cs.x + v1*cs.y) * mul);
        }
      }
    }
  } else {
    const int fcb = (bn & 2047) + wn*64 + lm;
    #pragma unroll
    for (int i = 0; i < 4; ++i) {
      const int t0 = tok0 + i*16 + quad*4;
      const int b  = t0 >> 11;
      const int tl = t0 & (TT-1);
      #pragma unroll
      for (int j = 0; j < 4; ++j) {
        const int c    = fcb + j*16;
        const int head = c >> 7;
        const int d    = c & 127;
        short4v o;
        #pragma unroll
        for (int r = 0; r < 4; ++r) o[r] = bfbits(acc[i][j][r]);
        *(short4v*)(Vt + ((size_t)(b*HEADS + head)*HDIM + d)*TT + tl) = o;
      }
    }
  }
}

// ---------------------------------------------------------------------------
// Causal flash attention, paired q-tiles processed sequentially (uniform work,
// no spill). Fixed-max softmax p = 2^(s' - FML2), Q pre-scaled by scale*log2e.
// ---------------------------------------------------------------------------
__global__ __launch_bounds__(256, 3)
void flash_attn(const __hip_bfloat16* __restrict__ Qh,
                const __hip_bfloat16* __restrict__ Kh,
                const __hip_bfloat16* __restrict__ Vt,
                __hip_bfloat16* __restrict__ Out)
{
  const int tid  = threadIdx.x;
  const int lane = tid & 63;
  const int wv   = tid >> 6;
  const int lm   = lane & 15;
  const int quad = lane >> 4;
  const int jA   = blockIdx.x;            // 0..15
  const int bh   = blockIdx.y;
  const int b    = bh >> 4;
  const int h    = bh & 15;

  __shared__ __hip_bfloat16 sK[64*136];
  __shared__ __hip_bfloat16 sV[128*72];
  __shared__ __hip_bfloat16 sP[4][16*72];

  const float FML2 = 8.0f * 1.4426950408889634f;

  const int rk0 = tid >> 4;
  const int ck  = (tid & 15) * 8;
  const int dv0 = tid >> 3;
  const int cv  = (tid & 7) * 8;
  const __hip_bfloat16* KpBase = Kh + (size_t)bh*TT*HDIM + (size_t)rk0*HDIM + ck;
  const __hip_bfloat16* VpBase = Vt + (size_t)bh*HDIM*TT + (size_t)dv0*TT + cv;

  #pragma unroll
  for (int pass = 0; pass < 2; ++pass) {
    const int q0 = (pass == 0 ? jA : 31 - jA) * 64;

    short8 aq[4];
    {
      const __hip_bfloat16* qp = Qh + ((size_t)bh*TT + q0 + wv*16 + lm)*HDIM + quad*8;
      #pragma unroll
      for (int kd=0;kd<4;kd++) aq[kd] = *(const short8*)(qp + kd*32);
    }

    float l_p[4] = {0,0,0,0};
    f32x4 acc_o[8];
    #pragma unroll
    for (int i=0;i<8;i++) acc_o[i] = (f32x4){0.f,0.f,0.f,0.f};

    const __hip_bfloat16* Kp = KpBase;
    const __hip_bfloat16* Vp = VpBase;
    short8 pk[4], pv[4];
    #pragma unroll
    for (int it=0;it<4;++it) {
      pk[it] = *(const short8*)(Kp + (size_t)it*16*HDIM);
      pv[it] = *(const short8*)(Vp + (size_t)it*32*TT);
    }
    Kp += (size_t)64*HDIM; Vp += 64;

    for (int kv0 = 0; kv0 <= q0; kv0 += 64) {
      __syncthreads();
      #pragma unroll
      for (int it=0;it<4;++it) {
        *(short8*)(&sK[(it*16 + rk0)*136 + ck]) = pk[it];
        *(short8*)(&sV[(it*32 + dv0)*72 + cv])  = pv[it];
      }
      if (kv0 + 64 <= q0) {
        #pragma unroll
        for (int it=0;it<4;++it) {
          pk[it] = *(const short8*)(Kp + (size_t)it*16*HDIM);
          pv[it] = *(const short8*)(Vp + (size_t)it*32*TT);
        }
        Kp += (size_t)64*HDIM; Vp += 64;
      }
      __syncthreads();

      f32x4 accs[4];
      #pragma unroll
      for (int nt=0;nt<4;nt++) accs[nt] = (f32x4){0.f,0.f,0.f,0.f};
      #pragma unroll
      for (int kd=0;kd<4;kd++)
        #pragma unroll
        for (int nt=0;nt<4;nt++) {
          short8 bk = *(const short8*)(&sK[(nt*16 + lm)*136 + kd*32 + quad*8]);
          accs[nt] = __builtin_amdgcn_mfma_f32_16x16x32_bf16(aq[kd], bk, accs[nt], 0,0,0);
        }

      const int rowb = q0 + wv*16 + quad*4;
      const bool diag = (kv0 == q0);
      #pragma unroll
      for (int nt=0;nt<4;nt++)
        #pragma unroll
        for (int r=0;r<4;r++) {
          float p = exp2f(accs[nt][r] - FML2);
          if (diag && (kv0 + nt*16 + lm > rowb + r)) p = 0.f;
          l_p[r] += p;
          sP[wv][(quad*4 + r)*72 + nt*16 + lm] = __float2bfloat16(p);
        }

      #pragma unroll
      for (int kd2=0;kd2<2;kd2++) {
        short8 ap = *(const short8*)(&sP[wv][lm*72 + kd2*32 + quad*8]);
        #pragma unroll
        for (int nt2=0;nt2<8;nt2++) {
          short8 bvv = *(const short8*)(&sV[(nt2*16 + lm)*72 + kd2*32 + quad*8]);
          acc_o[nt2] = __builtin_amdgcn_mfma_f32_16x16x32_bf16(ap, bvv, acc_o[nt2], 0,0,0);
        }
      }
    }

    #pragma unroll
    for (int off=1; off<16; off<<=1)
      #pragma unroll
      for (int r=0;r<4;r++) l_p[r] += __shfl_xor(l_p[r], off);
    #pragma unroll
    for (int r=0;r<4;r++) l_p[r] = 1.f / l_p[r];

    #pragma unroll
    for (int nt2=0;nt2<8;nt2++)
      #pragma unroll
      for (int r=0;r<4;r++) {
        int t = q0 + wv*16 + quad*4 + r;
        Out[((size_t)b*TT + t)*INNER + (size_t)h*HDIM + nt2*16 + lm] =
          __float2bfloat16(acc_o[nt2][r] * l_p[r]);
      }
  }
}

// ---------------------------------------------------------------------------
extern "C" void kernel_launch(void* const* d_in, const int* in_sizes, int n_in,
                              void* d_out, int out_size, void* d_ws, size_t ws_size,
                              hipStream_t stream)
{
  (void)in_sizes; (void)n_in; (void)out_size; (void)ws_size;
  const float* x     = (const float*)d_in[0];
  const float* Wqkv  = (const float*)d_in[1];
  const float* Wproj = (const float*)d_in[2];
  float* out = (float*)d_out;

  // Workspace (100.66 MB, R3-proven size):
  //  [0, 16.78): xb -> attn_out (xb dead after gemm_qkv)
  //  [16.78, 41.94): Wqkvb -> Wprojb overlay (Wqkvb dead after gemm_qkv)
  //  [41.94, 50.33): rope table (1 MB used; dead after gemm_qkv)
  //  [50.33, 67.11): Qh  [67.11, 83.89): Kh  [83.89, 100.66): Vt
  char* ws = (char*)d_ws;
  __hip_bfloat16* xb       = (__hip_bfloat16*)ws;
  __hip_bfloat16* attn_out = xb;
  char* p1 = ws + (size_t)NTOK*DMODEL*2;
  __hip_bfloat16* Wqkvb  = (__hip_bfloat16*)p1;
  __hip_bfloat16* Wprojb = (__hip_bfloat16*)p1;
  char* p2 = p1 + (size_t)E3*DMODEL*2;
  float2* ropeTab = (float2*)p2;
  char* p3 = p2 + (size_t)DMODEL*INNER*2;   // 8.39 MB slot (table uses 1 MB)
  const size_t hsz = (size_t)BB*HEADS*TT*HDIM*2;
  __hip_bfloat16* Qh = (__hip_bfloat16*)p3;
  __hip_bfloat16* Kh = (__hip_bfloat16*)(p3 + hsz);
  __hip_bfloat16* Vt = (__hip_bfloat16*)(p3 + 2*hsz);

  prep<<<dim3(NBX + NBW + NBT), dim3(256), 0, stream>>>(x, Wqkv, xb, Wqkvb, ropeTab);

  gemm_qkv3<<<dim3(768), dim3(512), 0, stream>>>(xb, Wqkvb, ropeTab, Qh, Kh, Vt);

  // Wqkvb + table dead; overlay Wprojb.
  cvt_bf16<<<dim3(DMODEL*INNER/2048), dim3(256), 0, stream>>>(Wproj, Wprojb, DMODEL*INNER);

  flash_attn<<<dim3(TT/128, BB*HEADS), dim3(256), 0, stream>>>(Qh, Kh, Vt, attn_out);

  gemm_lds<float>
    <<<dim3(INNER/128, NTOK/128), dim3(256), 0, stream>>>(attn_out, Wprojb, out, NTOK, INNER, DMODEL);
}